// Round 3
// baseline (6131.263 us; speedup 1.0000x reference)
//
#include <hip/hip_runtime.h>
#include <hip/hip_bf16.h>
#include <hip/hip_fp16.h>
#include <cstddef>

// Problem constants: B=64, T=512, D=1024, H=1024
#define BATCH 64
#define TT    512
#define DD    1024
#define HH    1024

typedef _Float16 f16x8 __attribute__((ext_vector_type(8)));
typedef float    f32x4 __attribute__((ext_vector_type(4)));

// ---------------- Kernel A: xp = x @ Wx + bias, written into d_out ----------
#define BM 64
#define BN 64
#define BK 16
#define TM 4
#define TN 4

__global__ __launch_bounds__(256) void gemm_xp(
    const float* __restrict__ A,    // [M, K] = x
    const float* __restrict__ Bw,   // [K, N] = Wx
    const float* __restrict__ bias, // [N]
    float* __restrict__ C)          // [M, N] -> xp (into d_out)
{
    const int N = HH;
    const int K = DD;

    __shared__ float As[BK][BM + 1];
    __shared__ float Bs[BK][BN];

    const int tid  = threadIdx.x;
    const int brow = blockIdx.y * BM;
    const int bcol = blockIdx.x * BN;

    const int tcol = (tid % 16) * TN;
    const int trow = (tid / 16) * TM;

    float acc[TM][TN];
#pragma unroll
    for (int m = 0; m < TM; ++m)
#pragma unroll
        for (int n = 0; n < TN; ++n) acc[m][n] = 0.f;

    for (int k0 = 0; k0 < K; k0 += BK) {
#pragma unroll
        for (int i = tid; i < BM * BK; i += 256) {
            int r = i / BK, c = i % BK;
            As[c][r] = A[(size_t)(brow + r) * K + (k0 + c)];
        }
#pragma unroll
        for (int i = tid; i < BK * BN; i += 256) {
            int r = i / BN, c = i % BN;
            Bs[r][c] = Bw[(size_t)(k0 + r) * N + (bcol + c)];
        }
        __syncthreads();

#pragma unroll
        for (int k = 0; k < BK; ++k) {
            float a[TM], bv[TN];
#pragma unroll
            for (int m = 0; m < TM; ++m) a[m] = As[k][trow + m];
#pragma unroll
            for (int n = 0; n < TN; ++n) bv[n] = Bs[k][tcol + n];
#pragma unroll
            for (int m = 0; m < TM; ++m)
#pragma unroll
                for (int n = 0; n < TN; ++n) acc[m][n] += a[m] * bv[n];
        }
        __syncthreads();
    }

#pragma unroll
    for (int m = 0; m < TM; ++m) {
        size_t row = (size_t)(brow + trow + m) * N;
#pragma unroll
        for (int n = 0; n < TN; ++n) {
            int col = bcol + tcol + n;
            C[row + col] = acc[m][n] + bias[col];
        }
    }
}

// ---------------- Kernel B0: Wh f32 -> fp16, MFMA-B-fragment order ----------
// Whf[(((cg*32 + kk)*64) + lane)*8 + e] = Wh[k][col]
//   k = kk*32 + (lane>>4)*8 + e, col = cg*16 + (lane&15).
// Also zeroes the 4 group-barrier counters (deterministic per launch).
__global__ __launch_bounds__(256) void convert_whf(
    const float* __restrict__ Wh, _Float16* __restrict__ Whf,
    unsigned int* __restrict__ ctr)
{
    if (blockIdx.x == 0 && threadIdx.x < 4) ctr[threadIdx.x] = 0u;

    int tid = blockIdx.x * 256 + threadIdx.x;   // tid = k*1024 + col
    int k   = tid >> 10;
    int col = tid & 1023;
    float v = Wh[tid];
    int cg   = col >> 4;
    int kk   = k >> 5;
    int lane = ((k >> 3) & 3) * 16 + (col & 15);
    int e    = k & 7;
    Whf[((size_t)(cg * 32 + kk) * 64 + lane) * 8 + e] = (_Float16)v;
}

// ---------------- Kernel B: persistent scan, B-frags resident in VGPRs -----
// 64 blocks x 256 threads (4 waves). Block: bg = bid&3, cgq = bid>>2.
// Wave w handles tile (bg, cg = cgq*4 + w): 16 batches x 16 cols.
// 4 independent group barriers (16 blocks sharing bg) via device-scope
// atomics; monotonic per-step targets. h double-buffered fp16 in d_ws.
__global__ __launch_bounds__(256, 1) void rnn_persist(
    const _Float16* __restrict__ Whf,   // frag-ordered [64][32][64][8]
    _Float16* __restrict__ hb0,         // [64][1024] fp16
    _Float16* __restrict__ hb1,         // [64][1024] fp16
    float* __restrict__ out,            // [64][512][1024]; xp -> h in place
    unsigned int* __restrict__ ctr)     // [4] group barrier counters
{
    const int bid  = blockIdx.x;
    const int bg   = bid & 3;
    const int cgq  = bid >> 2;
    const int w    = threadIdx.x >> 6;
    const int cg   = cgq * 4 + w;
    const int lane = threadIdx.x & 63;
    const int l15  = lane & 15;
    const int lq   = lane >> 4;
    const int col  = cg * 16 + l15;

    // Load B fragments once: 32 x f16x8 = 128 VGPRs, resident for all steps.
    f16x8 bfrag[32];
    {
        const f16x8* wp = (const f16x8*)Whf + ((size_t)cg * 32 * 64 + lane);
#pragma unroll
        for (int kk = 0; kk < 32; ++kk) bfrag[kk] = wp[(size_t)kk * 64];
    }

    _Float16* hb[2] = {hb0, hb1};
    unsigned int* myc = ctr + bg;

    for (int t = 0; t < TT; ++t) {
        f32x4 acc = {0.f, 0.f, 0.f, 0.f};

        if (t > 0) {
            const _Float16* hp = hb[(t + 1) & 1];
            const _Float16* ap = hp + (size_t)(bg * 16 + l15) * HH + lq * 8;
            f16x8 a[32];
#pragma unroll
            for (int kk = 0; kk < 32; ++kk)
                a[kk] = *(const f16x8*)(ap + (size_t)kk * 32);
#pragma unroll
            for (int kk = 0; kk < 32; ++kk)
                acc = __builtin_amdgcn_mfma_f32_16x16x32_f16(a[kk], bfrag[kk], acc, 0, 0, 0);
        }

        _Float16* hn = hb[t & 1];
#pragma unroll
        for (int v = 0; v < 4; ++v) {
            int b = bg * 16 + lq * 4 + v;   // C/D: row = 4*(l>>4)+v, col = l&15
            size_t o = ((size_t)b * TT + t) * HH + col;
            float hv = tanhf(acc[v] + out[o]);
            out[o] = hv;
            hn[(size_t)b * HH + col] = (_Float16)hv;
        }

        if (t < TT - 1) {
            // Group barrier: 16 blocks sharing bg.
            __syncthreads();
            if (threadIdx.x == 0) {
                __threadfence();
                __hip_atomic_fetch_add(myc, 1u, __ATOMIC_RELEASE, __HIP_MEMORY_SCOPE_AGENT);
                unsigned int tgt = 16u * (unsigned)(t + 1);
                while (__hip_atomic_load(myc, __ATOMIC_ACQUIRE, __HIP_MEMORY_SCOPE_AGENT) < tgt) {
                    __builtin_amdgcn_s_sleep(1);
                }
            }
            __syncthreads();
        }
    }
}

extern "C" void kernel_launch(void* const* d_in, const int* in_sizes, int n_in,
                              void* d_out, int out_size, void* d_ws, size_t ws_size,
                              hipStream_t stream) {
    const float* x    = (const float*)d_in[0]; // [B, T, D]
    const float* Wx   = (const float*)d_in[1]; // [D, H]
    const float* Wh   = (const float*)d_in[2]; // [H, H]
    const float* bias = (const float*)d_in[3]; // [H]

    float* out = (float*)d_out;                // [B, T, H]

    // Workspace: Whf (2 MB) | hb0 (128 KB) | hb1 (128 KB) | ctr (16 B)
    _Float16* Whf = (_Float16*)d_ws;
    _Float16* hb0 = Whf + (1u << 20);
    _Float16* hb1 = hb0 + BATCH * HH;
    unsigned int* ctr = (unsigned int*)(hb1 + BATCH * HH);

    // Wh -> fp16 frag order; also zeroes barrier counters.
    convert_whf<<<4096, 256, 0, stream>>>(Wh, Whf, ctr);

    // xp = x @ Wx + bias -> d_out
    dim3 gridA(HH / BN, (BATCH * TT) / BM);
    gemm_xp<<<gridA, 256, 0, stream>>>(x, Wx, bias, out);

    // Whole scan in one persistent kernel (64 blocks, co-resident).
    rnn_persist<<<64, 256, 0, stream>>>(Whf, hb0, hb1, out, ctr);
}